// Round 6
// baseline (97.062 us; speedup 1.0000x reference)
//
#include <hip/hip_runtime.h>

#define NB 8192
#define EPS_BN 1e-5f

// padded LDS index: +4 floats every 32 => stride-16B lane patterns are
// conflict-free while float4/float2 alignment is preserved (4 | pad).
#define PADX(i) ((i) + ((((i) >> 5)) << 2))

using bf16x8 = __attribute__((ext_vector_type(8))) __bf16;
using bf16x4 = __attribute__((ext_vector_type(4))) __bf16;
using f32x4  = __attribute__((ext_vector_type(4))) float;

// ---------------------------------------------------------------------------
// Kernel 1 (rewritten): conv stack + LIF.
// - BN folded into weights ONCE per block, staged to LDS in [ci][k][ch] layout
//   -> inner-loop weight fetch = one aligned ds_read_b128, (half-)wave-uniform
//   (broadcast, conflict-free), no scalar-load stalls, no per-thread BN math.
// - conv3 remapped (pos = tid&31, ch-quad = tid>>5): no duplicated work.
// - conv1 reads x directly from global (L1/L2), no xs tile.
// fp32 accumulation, same ci-major/k-minor order as previous rounds.
// ---------------------------------------------------------------------------
__global__ __launch_bounds__(256) void conv_lif_kernel(
    const float* __restrict__ x,
    const float* __restrict__ w1, const float* __restrict__ b1,
    const float* __restrict__ g1, const float* __restrict__ be1,
    const float* __restrict__ m1, const float* __restrict__ v1,
    const float* __restrict__ w2, const float* __restrict__ b2,
    const float* __restrict__ g2, const float* __restrict__ be2,
    const float* __restrict__ m2, const float* __restrict__ v2,
    const float* __restrict__ w3, const float* __restrict__ b3,
    const float* __restrict__ g3, const float* __restrict__ be3,
    const float* __restrict__ m3, const float* __restrict__ v3,
    float* __restrict__ spatial_out,        // [B][32]
    unsigned int* __restrict__ spk)         // [B][32] bitmask per (b,t)
{
    __shared__ alignas(16) float wA[64];        // conv1 folded [c][8] (k<7 used)
    __shared__ float bA[8];
    __shared__ alignas(16) float wB[640];       // conv2 folded [(ci*5+k)][16]
    __shared__ float bB[16];
    __shared__ alignas(16) float wC[1536];      // conv3 folded [(ci*3+k)][32]
    __shared__ float bC[32];
    __shared__ alignas(16) float c1[8 * 292];   // logical idx pos+2, PADX'd
    __shared__ alignas(16) float c2[16 * 76];   // logical idx pos+1, PADX'd
    __shared__ alignas(16) float c3[32 * 33];   // +1 pad for LIF column reads

    const int b   = blockIdx.x;
    const int tid = threadIdx.x;

    // ---- fold BN into weights/biases, stage to LDS (per block; cheap) ----
    for (int j = tid; j < 640; j += 256) {
        int c = j & 15, t = j >> 4, ci = t / 5, k = t - 5 * ci;
        float inv = g2[c] * rsqrtf(v2[c] + EPS_BN);
        wB[j] = w2[(c * 8 + ci) * 5 + k] * inv;
    }
    for (int j = tid; j < 1536; j += 256) {
        int c = j & 31, t = j >> 5, ci = t / 3, k = t - 3 * ci;
        float inv = g3[c] * rsqrtf(v3[c] + EPS_BN);
        wC[j] = w3[(c * 16 + ci) * 3 + k] * inv;
    }
    if (tid < 64) {
        int c = tid >> 3, k = tid & 7;
        wA[tid] = (k < 7) ? w1[c * 7 + k] * (g1[c] * rsqrtf(v1[c] + EPS_BN)) : 0.f;
    } else if (tid < 72) {
        int c = tid - 64;
        float inv = g1[c] * rsqrtf(v1[c] + EPS_BN);
        bA[c] = (b1[c] - m1[c]) * inv + be1[c];
    } else if (tid >= 80 && tid < 96) {
        int c = tid - 80;
        float inv = g2[c] * rsqrtf(v2[c] + EPS_BN);
        bB[c] = (b2[c] - m2[c]) * inv + be2[c];
    } else if (tid >= 96 && tid < 128) {
        int c = tid - 96;
        float inv = g3[c] * rsqrtf(v3[c] + EPS_BN);
        bC[c] = (b3[c] - m3[c]) * inv + be3[c];
    } else if (tid >= 128 && tid < 144) {
        int j = tid - 128;                  // c1 front zeros: 8 rows x 2
        c1[(j >> 1) * 292 + (j & 1)] = 0.f;
    } else if (tid >= 144 && tid < 160) {
        c2[(tid - 144) * 76] = 0.f;         // c2 front zeros
    }
    __syncthreads();

    // ---- conv1: thread = position t (256), all 8 channels; x from global ----
    {
        const float* xb = x + (size_t)b * 1024;
        const int t = tid;
        float4 gb = reinterpret_cast<const float4*>(xb)[t];          // 4t..4t+3
        float4 ga = make_float4(0.f, 0.f, 0.f, 0.f);
        if (t > 0) ga = reinterpret_cast<const float4*>(xb)[t - 1];  // 4t-4..4t-1
        float win[7] = {ga.y, ga.z, ga.w, gb.x, gb.y, gb.z, gb.w};
        #pragma unroll
        for (int c = 0; c < 8; c++) {
            float acc = bA[c];
            #pragma unroll
            for (int k = 0; k < 7; k++) acc = fmaf(wA[c * 8 + k], win[k], acc);
            c1[c * 292 + PADX(2 + t)] = fmaxf(acc, 0.f);
        }
    }
    __syncthreads();

    // ---- conv2: thread = (pos 64, ch-quad); weights: uniform b128 from LDS ----
    {
        const int p  = tid & 63;
        const int cg = (tid >> 6) << 2;          // wave-uniform
        float a0 = bB[cg], a1 = bB[cg + 1], a2 = bB[cg + 2], a3 = bB[cg + 3];
        #pragma unroll
        for (int ci = 0; ci < 8; ci++) {
            const float* row = &c1[ci * 292];
            float4 va = *reinterpret_cast<const float4*>(&row[PADX(4 * p)]);
            float  v4 = row[PADX(4 * p + 4)];
            float win[5] = {va.x, va.y, va.z, va.w, v4};
            #pragma unroll
            for (int k = 0; k < 5; k++) {
                float4 wv = *reinterpret_cast<const float4*>(&wB[(ci * 5 + k) * 16 + cg]);
                a0 = fmaf(wv.x, win[k], a0);
                a1 = fmaf(wv.y, win[k], a1);
                a2 = fmaf(wv.z, win[k], a2);
                a3 = fmaf(wv.w, win[k], a3);
            }
        }
        c2[(cg + 0) * 76 + PADX(1 + p)] = fmaxf(a0, 0.f);
        c2[(cg + 1) * 76 + PADX(1 + p)] = fmaxf(a1, 0.f);
        c2[(cg + 2) * 76 + PADX(1 + p)] = fmaxf(a2, 0.f);
        c2[(cg + 3) * 76 + PADX(1 + p)] = fmaxf(a3, 0.f);
    }
    __syncthreads();

    // ---- conv3: thread = (pos 32, ch-quad of 8); NO duplicated work ----
    {
        const int p  = tid & 31;
        const int c4 = (tid >> 5) << 2;          // 0,4,..,28 (half-wave uniform)
        float a0 = bC[c4], a1 = bC[c4 + 1], a2 = bC[c4 + 2], a3 = bC[c4 + 3];
        #pragma unroll
        for (int ci = 0; ci < 16; ci++) {
            const float* row = &c2[ci * 76];
            float2 vab = *reinterpret_cast<const float2*>(&row[PADX(2 * p)]);
            float  vc  = row[PADX(2 * p + 2)];
            float win[3] = {vab.x, vab.y, vc};
            #pragma unroll
            for (int k = 0; k < 3; k++) {
                float4 wv = *reinterpret_cast<const float4*>(&wC[(ci * 3 + k) * 32 + c4]);
                a0 = fmaf(wv.x, win[k], a0);
                a1 = fmaf(wv.y, win[k], a1);
                a2 = fmaf(wv.z, win[k], a2);
                a3 = fmaf(wv.w, win[k], a3);
            }
        }
        c3[(c4 + 0) * 33 + p] = fmaxf(a0, 0.f);
        c3[(c4 + 1) * 33 + p] = fmaxf(a1, 0.f);
        c3[(c4 + 2) * 33 + p] = fmaxf(a2, 0.f);
        c3[(c4 + 3) * 33 + p] = fmaxf(a3, 0.f);
    }
    __syncthreads();

    // ---- spatial mean + LIF scan (lanes 0..31 of wave 0) ----
    if (tid < 32) {
        float s = 0.f;
        #pragma unroll
        for (int t = 0; t < 32; t++) s += c3[tid * 33 + t];
        spatial_out[(size_t)b * 32 + tid] = s * 0.03125f;

        float mem = 0.f;
        #pragma unroll
        for (int t = 0; t < 32; t++) {
            mem = __fadd_rn(__fmul_rn(0.9f, mem), c3[tid * 33 + t]);
            bool spike = mem > 0.5f;
            mem = spike ? 0.f : mem;
            unsigned long long msk = __ballot(spike);
            if (tid == 0) spk[(size_t)b * 32 + t] = (unsigned int)(msk & 0xffffffffull);
        }
    }
}

// ---------------------------------------------------------------------------
// Kernel 2: MFMA-batched LSTM + FC head (UNCHANGED from round 5).
// ---------------------------------------------------------------------------
__device__ inline float sigm(float x) {
    return __builtin_amdgcn_rcpf(1.f + __expf(-x));
}
__device__ inline float tanh_(float x) {
    return fmaf(2.f, __builtin_amdgcn_rcpf(1.f + __expf(-2.f * x)), -1.f);
}
__device__ inline bf16x8 ldfrag(const float* __restrict__ p) {
    bf16x8 r;
    #pragma unroll
    for (int i = 0; i < 8; i++) r[i] = (__bf16)p[i];
    return r;
}

__global__ __launch_bounds__(64, 2) void lstm_fc_mfma_kernel(
    const unsigned int* __restrict__ spk,   // [B][32]
    const float* __restrict__ w_ih, const float* __restrict__ w_hh,
    const float* __restrict__ b_ih, const float* __restrict__ b_hh,
    const float* __restrict__ fc1w, const float* __restrict__ fc1b,
    const float* __restrict__ fc2w, const float* __restrict__ fc2b,
    const float* __restrict__ fc3w, const float* __restrict__ fc3b,
    const float* __restrict__ spatial_in,   // [B][32]
    float* __restrict__ out0,               // [B][4]
    float* __restrict__ hlast_out)          // [B][32]
{
    const int l    = threadIdx.x;
    const int row  = l & 15;                // batch-within-tile (and X gate-row)
    const int q    = l >> 4;                // k-group 0..3
    const int base = blockIdx.x * 16;

    __shared__ unsigned int mlds[512];      // [t][16] spike masks
    __shared__ __bf16 hlds[640];            // [16][40]
    __shared__ __bf16 zlds[1152];           // [16][72]

    for (int i = l; i < 512; i += 64) {
        int j = i >> 5, t = i & 31;
        mlds[t * 16 + j] = spk[(size_t)(base + j) * 32 + t];
    }
    for (int i = l; i < 640; i += 64) hlds[i] = (__bf16)0.f;

    bf16x8 wih[8], whh[8];
    f32x4  bfr[8];
    #pragma unroll
    for (int T = 0; T < 8; T++) {
        wih[T] = ldfrag(w_ih + (size_t)(16 * T + row) * 32 + 8 * q);
        whh[T] = ldfrag(w_hh + (size_t)(16 * T + row) * 32 + 8 * q);
        const float* ba = b_ih + 16 * T + 4 * q;
        const float* bb = b_hh + 16 * T + 4 * q;
        f32x4 bf;
        #pragma unroll
        for (int i = 0; i < 4; i++) bf[i] = ba[i] + bb[i];
        bfr[T] = bf;
    }

    float cst[8];
    float hq[8];
    #pragma unroll
    for (int i = 0; i < 8; i++) { cst[i] = 0.f; hq[i] = 0.f; }

    #pragma unroll 1
    for (int t = 0; t < 32; t++) {
        unsigned int m  = mlds[t * 16 + row];
        unsigned int by = (m >> (q * 8)) & 0xFFu;
        union { bf16x8 v; unsigned int u[4]; } a1;
        a1.u[0] = ((by & 1u)        * 0x3F80u) | (((by >> 1) & 1u) * 0x3F800000u);
        a1.u[1] = (((by >> 2) & 1u) * 0x3F80u) | (((by >> 3) & 1u) * 0x3F800000u);
        a1.u[2] = (((by >> 4) & 1u) * 0x3F80u) | (((by >> 5) & 1u) * 0x3F800000u);
        a1.u[3] = (((by >> 6) & 1u) * 0x3F80u) | (((by >> 7) & 1u) * 0x3F800000u);
        bf16x8 a2 = *reinterpret_cast<bf16x8*>(&hlds[row * 40 + q * 8]);

        f32x4 acc[8];
        #pragma unroll
        for (int T = 0; T < 8; T++) {
            acc[T] = __builtin_amdgcn_mfma_f32_16x16x32_bf16(wih[T], a1.v, bfr[T], 0, 0, 0);
            acc[T] = __builtin_amdgcn_mfma_f32_16x16x32_bf16(whh[T], a2,   acc[T], 0, 0, 0);
        }

        #pragma unroll
        for (int j = 0; j < 4; j++) {
            float iv = sigm(acc[0][j]);
            float fv = sigm(acc[2][j]);
            float gv = tanh_(acc[4][j]);
            float ov = sigm(acc[6][j]);
            cst[j] = fmaf(fv, cst[j], iv * gv);
            hq[j]  = ov * tanh_(cst[j]);
            float iv2 = sigm(acc[1][j]);
            float fv2 = sigm(acc[3][j]);
            float gv2 = tanh_(acc[5][j]);
            float ov2 = sigm(acc[7][j]);
            cst[4 + j] = fmaf(fv2, cst[4 + j], iv2 * gv2);
            hq[4 + j]  = ov2 * tanh_(cst[4 + j]);
        }

        bf16x4 hv0, hv1;
        #pragma unroll
        for (int j = 0; j < 4; j++) { hv0[j] = (__bf16)hq[j]; hv1[j] = (__bf16)hq[4 + j]; }
        *reinterpret_cast<bf16x4*>(&hlds[row * 40 + 4 * q])      = hv0;
        *reinterpret_cast<bf16x4*>(&hlds[row * 40 + 16 + 4 * q]) = hv1;
    }

    {
        f32x4 lo, hi;
        #pragma unroll
        for (int j = 0; j < 4; j++) { lo[j] = hq[j]; hi[j] = hq[4 + j]; }
        *reinterpret_cast<f32x4*>(hlast_out + (size_t)(base + row) * 32 + 4 * q)      = lo;
        *reinterpret_cast<f32x4*>(hlast_out + (size_t)(base + row) * 32 + 16 + 4 * q) = hi;
    }

    bf16x8 hf = *reinterpret_cast<bf16x8*>(&hlds[row * 40 + q * 8]);
    bf16x8 spf;
    {
        const float* sp = spatial_in + (size_t)(base + row) * 32 + 8 * q;
        #pragma unroll
        for (int i = 0; i < 8; i++) spf[i] = (__bf16)sp[i];
    }

    #pragma unroll
    for (int T = 0; T < 4; T++) {
        bf16x8 x0 = ldfrag(fc1w + (size_t)(16 * T + row) * 64 + 8 * q);
        bf16x8 x1 = ldfrag(fc1w + (size_t)(16 * T + row) * 64 + 32 + 8 * q);
        f32x4 c;
        #pragma unroll
        for (int i = 0; i < 4; i++) c[i] = fc1b[16 * T + 4 * q + i];
        f32x4 a = __builtin_amdgcn_mfma_f32_16x16x32_bf16(x0, hf,  c, 0, 0, 0);
        a       = __builtin_amdgcn_mfma_f32_16x16x32_bf16(x1, spf, a, 0, 0, 0);
        bf16x4 zv;
        #pragma unroll
        for (int i = 0; i < 4; i++) zv[i] = (__bf16)fmaxf(a[i], 0.f);
        *reinterpret_cast<bf16x4*>(&zlds[row * 72 + 16 * T + 4 * q]) = zv;
    }
    bf16x8 z1f0 = *reinterpret_cast<bf16x8*>(&zlds[row * 72 + 8 * q]);
    bf16x8 z1f1 = *reinterpret_cast<bf16x8*>(&zlds[row * 72 + 32 + 8 * q]);

    #pragma unroll
    for (int T = 0; T < 2; T++) {
        bf16x8 x0 = ldfrag(fc2w + (size_t)(16 * T + row) * 64 + 8 * q);
        bf16x8 x1 = ldfrag(fc2w + (size_t)(16 * T + row) * 64 + 32 + 8 * q);
        f32x4 c;
        #pragma unroll
        for (int i = 0; i < 4; i++) c[i] = fc2b[16 * T + 4 * q + i];
        f32x4 a = __builtin_amdgcn_mfma_f32_16x16x32_bf16(x0, z1f0, c, 0, 0, 0);
        a       = __builtin_amdgcn_mfma_f32_16x16x32_bf16(x1, z1f1, a, 0, 0, 0);
        bf16x4 zv;
        #pragma unroll
        for (int i = 0; i < 4; i++) zv[i] = (__bf16)fmaxf(a[i], 0.f);
        *reinterpret_cast<bf16x4*>(&hlds[row * 40 + 16 * T + 4 * q]) = zv;
    }
    bf16x8 z2f = *reinterpret_cast<bf16x8*>(&hlds[row * 40 + 8 * q]);

    {
        bf16x8 x3 = ldfrag(fc3w + (size_t)(row & 3) * 32 + 8 * q);
        f32x4 c;
        #pragma unroll
        for (int i = 0; i < 4; i++) c[i] = fc3b[i];
        f32x4 o = __builtin_amdgcn_mfma_f32_16x16x32_bf16(x3, z2f, c, 0, 0, 0);
        if (l < 16)
            *reinterpret_cast<f32x4*>(out0 + (size_t)(base + row) * 4) = o;
    }
}

// ---------------------------------------------------------------------------
extern "C" void kernel_launch(void* const* d_in, const int* in_sizes, int n_in,
                              void* d_out, int out_size, void* d_ws, size_t ws_size,
                              hipStream_t stream) {
    const float* x    = (const float*)d_in[0];
    const float* w1   = (const float*)d_in[1];
    const float* b1   = (const float*)d_in[2];
    const float* g1   = (const float*)d_in[3];
    const float* be1  = (const float*)d_in[4];
    const float* m1   = (const float*)d_in[5];
    const float* v1   = (const float*)d_in[6];
    const float* w2   = (const float*)d_in[7];
    const float* b2   = (const float*)d_in[8];
    const float* g2   = (const float*)d_in[9];
    const float* be2  = (const float*)d_in[10];
    const float* m2   = (const float*)d_in[11];
    const float* v2   = (const float*)d_in[12];
    const float* w3   = (const float*)d_in[13];
    const float* b3   = (const float*)d_in[14];
    const float* g3   = (const float*)d_in[15];
    const float* be3  = (const float*)d_in[16];
    const float* m3   = (const float*)d_in[17];
    const float* v3   = (const float*)d_in[18];
    const float* w_ih = (const float*)d_in[19];
    const float* w_hh = (const float*)d_in[20];
    const float* b_ih = (const float*)d_in[21];
    const float* b_hh = (const float*)d_in[22];
    const float* fc1w = (const float*)d_in[23];
    const float* fc1b = (const float*)d_in[24];
    const float* fc2w = (const float*)d_in[25];
    const float* fc2b = (const float*)d_in[26];
    const float* fc3w = (const float*)d_in[27];
    const float* fc3b = (const float*)d_in[28];

    float* out0    = (float*)d_out;                 // [8192][4]
    float* spatial = out0 + (size_t)NB * 4;         // [8192][32]
    float* hlast   = spatial + (size_t)NB * 32;     // [8192][32]
    unsigned int* spk = (unsigned int*)d_ws;        // [8192][32] bitmasks

    hipLaunchKernelGGL(conv_lif_kernel, dim3(NB), dim3(256), 0, stream,
                       x, w1, b1, g1, be1, m1, v1,
                       w2, b2, g2, be2, m2, v2,
                       w3, b3, g3, be3, m3, v3,
                       spatial, spk);

    hipLaunchKernelGGL(lstm_fc_mfma_kernel, dim3(NB / 16), dim3(64), 0, stream,
                       spk, w_ih, w_hh, b_ih, b_hh,
                       fc1w, fc1b, fc2w, fc2b, fc3w, fc3b,
                       spatial, out0, hlast);
}

// Round 7
// 85.789 us; speedup vs baseline: 1.1314x; 1.1314x over previous
//
#include <hip/hip_runtime.h>

#define NB 8192
#define EPS_BN 1e-5f

// padded LDS index: +4 floats every 32 => stride-16B lane patterns are
// conflict-free while float4/float2 alignment is preserved (4 | pad).
#define PADX(i) ((i) + ((((i) >> 5)) << 2))

using bf16x8 = __attribute__((ext_vector_type(8))) __bf16;
using bf16x4 = __attribute__((ext_vector_type(4))) __bf16;
using f32x4  = __attribute__((ext_vector_type(4))) float;
using f32x2  = __attribute__((ext_vector_type(2))) float;

// folded-weight layout in d_ws (float offsets, after 1MB spk region):
//   0    wA1[64]   [k:8][c:8] (k<7 valid)          -> uniform s_load
//   64   bA1[8]
//   80   wB2[640]  [(ci*5+k)*16 + c]               -> LDS, b128 at 4cq
//   720  bB2[16]
//   736  wC3[1536] [(ci*3+k)*32 + c]               -> LDS, b128 at 4cq
//   2272 bC3[32]
#define WSF_OFF   262144           // floats: spk = 8192*32 uints = 1MB
#define FW_TOTAL  2304
#define FW_STAGE0 80               // staged region [80, 2304) -> 2224 floats = 556 f4
#define FW_STAGEN 556

// ---------------------------------------------------------------------------
// Kernel 0: fold BN into conv weights once (2304 threads, one j each).
// ---------------------------------------------------------------------------
__global__ __launch_bounds__(256) void fold_kernel(
    const float* __restrict__ w1, const float* __restrict__ b1,
    const float* __restrict__ g1, const float* __restrict__ be1,
    const float* __restrict__ m1, const float* __restrict__ v1,
    const float* __restrict__ w2, const float* __restrict__ b2,
    const float* __restrict__ g2, const float* __restrict__ be2,
    const float* __restrict__ m2, const float* __restrict__ v2,
    const float* __restrict__ w3, const float* __restrict__ b3,
    const float* __restrict__ g3, const float* __restrict__ be3,
    const float* __restrict__ m3, const float* __restrict__ v3,
    float* __restrict__ wsf)
{
    int j = blockIdx.x * 256 + threadIdx.x;
    if (j < 64) {                                   // wA1 [k][c]
        int k = j >> 3, c = j & 7;
        wsf[j] = (k < 7) ? w1[c * 7 + k] * (g1[c] * rsqrtf(v1[c] + EPS_BN)) : 0.f;
    } else if (j < 72) {                            // bA1
        int c = j - 64;
        float inv = g1[c] * rsqrtf(v1[c] + EPS_BN);
        wsf[j] = (b1[c] - m1[c]) * inv + be1[c];
    } else if (j >= 80 && j < 720) {                // wB2
        int i = j - 80, c = i & 15, t = i >> 4, ci = t / 5, k = t - 5 * ci;
        wsf[j] = w2[(c * 8 + ci) * 5 + k] * (g2[c] * rsqrtf(v2[c] + EPS_BN));
    } else if (j >= 720 && j < 736) {               // bB2
        int c = j - 720;
        float inv = g2[c] * rsqrtf(v2[c] + EPS_BN);
        wsf[j] = (b2[c] - m2[c]) * inv + be2[c];
    } else if (j >= 736 && j < 2272) {              // wC3
        int i = j - 736, c = i & 31, t = i >> 5, ci = t / 3, k = t - 3 * ci;
        wsf[j] = w3[(c * 16 + ci) * 3 + k] * (g3[c] * rsqrtf(v3[c] + EPS_BN));
    } else if (j >= 2272 && j < 2304) {             // bC3
        int c = j - 2272;
        float inv = g3[c] * rsqrtf(v3[c] + EPS_BN);
        wsf[j] = (b3[c] - m3[c]) * inv + be3[c];
    }
}

// ---------------------------------------------------------------------------
// Kernel 1: conv stack + LIF. One block (256 thr) per batch element.
// Round-5 skeleton (xs staging, padded activation tiles) + pre-folded weights
// (straight f4 copy to LDS) + 4ch x 2pos register blocking on 2 waves for
// conv2/conv3 (no duplicated work) + packed-fp32 FMA pairs over channels.
// Accumulation order per output: ci-major, k-minor (unchanged since round 2).
// ---------------------------------------------------------------------------
__device__ inline f32x2 pkfma(f32x2 a, f32x2 b, f32x2 c) {
    return __builtin_elementwise_fma(a, b, c);
}

__global__ __launch_bounds__(256) void conv_lif_kernel(
    const float* __restrict__ x,
    const float* __restrict__ wsf,          // folded weights (global)
    float* __restrict__ spatial_out,        // [B][32]
    unsigned int* __restrict__ spk)         // [B][32] bitmask per (b,t)
{
    __shared__ alignas(16) float xs[1168];          // [8 zero | 1024 | 8 zero] PADX'd
    __shared__ alignas(16) float c1[8 * 292];       // logical idx pos+2, PADX'd
    __shared__ alignas(16) float c2[16 * 76];       // logical idx pos+1, PADX'd
    __shared__ alignas(16) float c3[32 * 33];       // +1 pad for LIF column reads
    __shared__ alignas(16) float wS[2224];          // staged folded weights

    const int b   = blockIdx.x;
    const int tid = threadIdx.x;

    float* wB2 = wS;            // 640
    float* bB2 = wS + 640;      // 16
    float* wC3 = wS + 656;      // 1536
    float* bC3 = wS + 2192;     // 32

    // ---- stage folded weights (coalesced f4 copy) + pads + x tile ----
    for (int i = tid; i < FW_STAGEN; i += 256) {
        reinterpret_cast<float4*>(wS)[i] =
            reinterpret_cast<const float4*>(wsf + FW_STAGE0)[i];
    }
    if (tid < 8) {
        xs[tid] = 0.f;
        xs[PADX(1032 + tid)] = 0.f;
    } else if (tid >= 32 && tid < 48) {
        int j = tid - 32;                   // c1 front zeros: 8 rows x 2
        c1[(j >> 1) * 292 + (j & 1)] = 0.f;
    } else if (tid >= 64 && tid < 80) {
        c2[(tid - 64) * 76] = 0.f;          // c2 front zeros
    }
    {
        float4 xv = reinterpret_cast<const float4*>(x + (size_t)b * 1024)[tid];
        *reinterpret_cast<float4*>(&xs[PADX(8 + 4 * tid)]) = xv;
    }
    __syncthreads();

    // ---- conv1: thread = position (256), 8 ch as 4 ch-pairs (pk) ----
    // weights: wave-uniform s_load from global wsf[k*8 + 2cp], bias wsf[64+2cp]
    {
        const int t    = tid;
        const int base = 4 * t + 4;
        float4 xa = *reinterpret_cast<const float4*>(&xs[PADX(base)]);
        float4 xb = *reinterpret_cast<const float4*>(&xs[PADX(base + 4)]);
        float win[7] = {xa.y, xa.z, xa.w, xb.x, xb.y, xb.z, xb.w};
        #pragma unroll
        for (int cp = 0; cp < 4; cp++) {
            f32x2 acc = *reinterpret_cast<const f32x2*>(wsf + 64 + 2 * cp);
            #pragma unroll
            for (int k = 0; k < 7; k++) {
                f32x2 wv = *reinterpret_cast<const f32x2*>(wsf + k * 8 + 2 * cp);
                f32x2 ws2 = {win[k], win[k]};
                acc = pkfma(wv, ws2, acc);
            }
            c1[(2 * cp + 0) * 292 + PADX(2 + t)] = fmaxf(acc[0], 0.f);
            c1[(2 * cp + 1) * 292 + PADX(2 + t)] = fmaxf(acc[1], 0.f);
        }
    }
    __syncthreads();

    // ---- conv2: 2 waves; thread = (pos p2 & p2+32) x (ch quad 4cq) ----
    if (tid < 128) {
        const int p2 = tid & 31;
        const int cq = tid >> 5;            // 0..3
        f32x2 b01 = *reinterpret_cast<const f32x2*>(&bB2[4 * cq]);
        f32x2 b23 = *reinterpret_cast<const f32x2*>(&bB2[4 * cq + 2]);
        f32x2 aP0c01 = b01, aP0c23 = b23;   // pos p2
        f32x2 aP1c01 = b01, aP1c23 = b23;   // pos p2+32
        #pragma unroll
        for (int ci = 0; ci < 8; ci++) {
            const float* row = &c1[ci * 292];
            float4 va = *reinterpret_cast<const float4*>(&row[PADX(4 * p2)]);
            float  v4 = row[PADX(4 * p2 + 4)];
            float4 vb = *reinterpret_cast<const float4*>(&row[PADX(4 * p2 + 128)]);
            float  v4b = row[PADX(4 * p2 + 132)];
            float wl[5] = {va.x, va.y, va.z, va.w, v4};
            float wh[5] = {vb.x, vb.y, vb.z, vb.w, v4b};
            #pragma unroll
            for (int k = 0; k < 5; k++) {
                f32x4 wv = *reinterpret_cast<const f32x4*>(&wB2[(ci * 5 + k) * 16 + 4 * cq]);
                f32x2 w01 = __builtin_shufflevector(wv, wv, 0, 1);
                f32x2 w23 = __builtin_shufflevector(wv, wv, 2, 3);
                f32x2 sl = {wl[k], wl[k]};
                f32x2 sh = {wh[k], wh[k]};
                aP0c01 = pkfma(w01, sl, aP0c01);
                aP0c23 = pkfma(w23, sl, aP0c23);
                aP1c01 = pkfma(w01, sh, aP1c01);
                aP1c23 = pkfma(w23, sh, aP1c23);
            }
        }
        c2[(4 * cq + 0) * 76 + PADX(1 + p2)]      = fmaxf(aP0c01[0], 0.f);
        c2[(4 * cq + 1) * 76 + PADX(1 + p2)]      = fmaxf(aP0c01[1], 0.f);
        c2[(4 * cq + 2) * 76 + PADX(1 + p2)]      = fmaxf(aP0c23[0], 0.f);
        c2[(4 * cq + 3) * 76 + PADX(1 + p2)]      = fmaxf(aP0c23[1], 0.f);
        c2[(4 * cq + 0) * 76 + PADX(33 + p2)]     = fmaxf(aP1c01[0], 0.f);
        c2[(4 * cq + 1) * 76 + PADX(33 + p2)]     = fmaxf(aP1c01[1], 0.f);
        c2[(4 * cq + 2) * 76 + PADX(33 + p2)]     = fmaxf(aP1c23[0], 0.f);
        c2[(4 * cq + 3) * 76 + PADX(33 + p2)]     = fmaxf(aP1c23[1], 0.f);
    }
    __syncthreads();

    // ---- conv3: 2 waves; thread = (pos p2 & p2+16) x (ch quad 4cq) ----
    if (tid < 128) {
        const int p2 = tid & 15;
        const int cq = tid >> 4;            // 0..7
        f32x2 b01 = *reinterpret_cast<const f32x2*>(&bC3[4 * cq]);
        f32x2 b23 = *reinterpret_cast<const f32x2*>(&bC3[4 * cq + 2]);
        f32x2 aP0c01 = b01, aP0c23 = b23;   // pos p2
        f32x2 aP1c01 = b01, aP1c23 = b23;   // pos p2+16
        #pragma unroll
        for (int ci = 0; ci < 16; ci++) {
            const float* row = &c2[ci * 76];
            float2 vab = *reinterpret_cast<const float2*>(&row[PADX(2 * p2)]);
            float  vc  = row[PADX(2 * p2 + 2)];
            float2 vab2 = *reinterpret_cast<const float2*>(&row[PADX(2 * p2 + 32)]);
            float  vc2  = row[PADX(2 * p2 + 34)];
            float wl[3] = {vab.x, vab.y, vc};
            float wh[3] = {vab2.x, vab2.y, vc2};
            #pragma unroll
            for (int k = 0; k < 3; k++) {
                f32x4 wv = *reinterpret_cast<const f32x4*>(&wC3[(ci * 3 + k) * 32 + 4 * cq]);
                f32x2 w01 = __builtin_shufflevector(wv, wv, 0, 1);
                f32x2 w23 = __builtin_shufflevector(wv, wv, 2, 3);
                f32x2 sl = {wl[k], wl[k]};
                f32x2 sh = {wh[k], wh[k]};
                aP0c01 = pkfma(w01, sl, aP0c01);
                aP0c23 = pkfma(w23, sl, aP0c23);
                aP1c01 = pkfma(w01, sh, aP1c01);
                aP1c23 = pkfma(w23, sh, aP1c23);
            }
        }
        c3[(4 * cq + 0) * 33 + p2]      = fmaxf(aP0c01[0], 0.f);
        c3[(4 * cq + 1) * 33 + p2]      = fmaxf(aP0c01[1], 0.f);
        c3[(4 * cq + 2) * 33 + p2]      = fmaxf(aP0c23[0], 0.f);
        c3[(4 * cq + 3) * 33 + p2]      = fmaxf(aP0c23[1], 0.f);
        c3[(4 * cq + 0) * 33 + p2 + 16] = fmaxf(aP1c01[0], 0.f);
        c3[(4 * cq + 1) * 33 + p2 + 16] = fmaxf(aP1c01[1], 0.f);
        c3[(4 * cq + 2) * 33 + p2 + 16] = fmaxf(aP1c23[0], 0.f);
        c3[(4 * cq + 3) * 33 + p2 + 16] = fmaxf(aP1c23[1], 0.f);
    }
    __syncthreads();

    // ---- spatial mean + LIF scan (lanes 0..31 of wave 0) ----
    if (tid < 32) {
        float s = 0.f;
        #pragma unroll
        for (int t = 0; t < 32; t++) s += c3[tid * 33 + t];
        spatial_out[(size_t)b * 32 + tid] = s * 0.03125f;

        float mem = 0.f;
        #pragma unroll
        for (int t = 0; t < 32; t++) {
            mem = __fadd_rn(__fmul_rn(0.9f, mem), c3[tid * 33 + t]);
            bool spike = mem > 0.5f;
            mem = spike ? 0.f : mem;
            unsigned long long msk = __ballot(spike);
            if (tid == 0) spk[(size_t)b * 32 + t] = (unsigned int)(msk & 0xffffffffull);
        }
    }
}

// ---------------------------------------------------------------------------
// Kernel 2: MFMA-batched LSTM + FC head (UNCHANGED from round 5).
// ---------------------------------------------------------------------------
__device__ inline float sigm(float x) {
    return __builtin_amdgcn_rcpf(1.f + __expf(-x));
}
__device__ inline float tanh_(float x) {
    return fmaf(2.f, __builtin_amdgcn_rcpf(1.f + __expf(-2.f * x)), -1.f);
}
__device__ inline bf16x8 ldfrag(const float* __restrict__ p) {
    bf16x8 r;
    #pragma unroll
    for (int i = 0; i < 8; i++) r[i] = (__bf16)p[i];
    return r;
}

__global__ __launch_bounds__(64, 2) void lstm_fc_mfma_kernel(
    const unsigned int* __restrict__ spk,   // [B][32]
    const float* __restrict__ w_ih, const float* __restrict__ w_hh,
    const float* __restrict__ b_ih, const float* __restrict__ b_hh,
    const float* __restrict__ fc1w, const float* __restrict__ fc1b,
    const float* __restrict__ fc2w, const float* __restrict__ fc2b,
    const float* __restrict__ fc3w, const float* __restrict__ fc3b,
    const float* __restrict__ spatial_in,   // [B][32]
    float* __restrict__ out0,               // [B][4]
    float* __restrict__ hlast_out)          // [B][32]
{
    const int l    = threadIdx.x;
    const int row  = l & 15;                // batch-within-tile (and X gate-row)
    const int q    = l >> 4;                // k-group 0..3
    const int base = blockIdx.x * 16;

    __shared__ unsigned int mlds[512];      // [t][16] spike masks
    __shared__ __bf16 hlds[640];            // [16][40]
    __shared__ __bf16 zlds[1152];           // [16][72]

    for (int i = l; i < 512; i += 64) {
        int j = i >> 5, t = i & 31;
        mlds[t * 16 + j] = spk[(size_t)(base + j) * 32 + t];
    }
    for (int i = l; i < 640; i += 64) hlds[i] = (__bf16)0.f;

    bf16x8 wih[8], whh[8];
    f32x4  bfr[8];
    #pragma unroll
    for (int T = 0; T < 8; T++) {
        wih[T] = ldfrag(w_ih + (size_t)(16 * T + row) * 32 + 8 * q);
        whh[T] = ldfrag(w_hh + (size_t)(16 * T + row) * 32 + 8 * q);
        const float* ba = b_ih + 16 * T + 4 * q;
        const float* bb = b_hh + 16 * T + 4 * q;
        f32x4 bf;
        #pragma unroll
        for (int i = 0; i < 4; i++) bf[i] = ba[i] + bb[i];
        bfr[T] = bf;
    }

    float cst[8];
    float hq[8];
    #pragma unroll
    for (int i = 0; i < 8; i++) { cst[i] = 0.f; hq[i] = 0.f; }

    #pragma unroll 1
    for (int t = 0; t < 32; t++) {
        unsigned int m  = mlds[t * 16 + row];
        unsigned int by = (m >> (q * 8)) & 0xFFu;
        union { bf16x8 v; unsigned int u[4]; } a1;
        a1.u[0] = ((by & 1u)        * 0x3F80u) | (((by >> 1) & 1u) * 0x3F800000u);
        a1.u[1] = (((by >> 2) & 1u) * 0x3F80u) | (((by >> 3) & 1u) * 0x3F800000u);
        a1.u[2] = (((by >> 4) & 1u) * 0x3F80u) | (((by >> 5) & 1u) * 0x3F800000u);
        a1.u[3] = (((by >> 6) & 1u) * 0x3F80u) | (((by >> 7) & 1u) * 0x3F800000u);
        bf16x8 a2 = *reinterpret_cast<bf16x8*>(&hlds[row * 40 + q * 8]);

        f32x4 acc[8];
        #pragma unroll
        for (int T = 0; T < 8; T++) {
            acc[T] = __builtin_amdgcn_mfma_f32_16x16x32_bf16(wih[T], a1.v, bfr[T], 0, 0, 0);
            acc[T] = __builtin_amdgcn_mfma_f32_16x16x32_bf16(whh[T], a2,   acc[T], 0, 0, 0);
        }

        #pragma unroll
        for (int j = 0; j < 4; j++) {
            float iv = sigm(acc[0][j]);
            float fv = sigm(acc[2][j]);
            float gv = tanh_(acc[4][j]);
            float ov = sigm(acc[6][j]);
            cst[j] = fmaf(fv, cst[j], iv * gv);
            hq[j]  = ov * tanh_(cst[j]);
            float iv2 = sigm(acc[1][j]);
            float fv2 = sigm(acc[3][j]);
            float gv2 = tanh_(acc[5][j]);
            float ov2 = sigm(acc[7][j]);
            cst[4 + j] = fmaf(fv2, cst[4 + j], iv2 * gv2);
            hq[4 + j]  = ov2 * tanh_(cst[4 + j]);
        }

        bf16x4 hv0, hv1;
        #pragma unroll
        for (int j = 0; j < 4; j++) { hv0[j] = (__bf16)hq[j]; hv1[j] = (__bf16)hq[4 + j]; }
        *reinterpret_cast<bf16x4*>(&hlds[row * 40 + 4 * q])      = hv0;
        *reinterpret_cast<bf16x4*>(&hlds[row * 40 + 16 + 4 * q]) = hv1;
    }

    {
        f32x4 lo, hi;
        #pragma unroll
        for (int j = 0; j < 4; j++) { lo[j] = hq[j]; hi[j] = hq[4 + j]; }
        *reinterpret_cast<f32x4*>(hlast_out + (size_t)(base + row) * 32 + 4 * q)      = lo;
        *reinterpret_cast<f32x4*>(hlast_out + (size_t)(base + row) * 32 + 16 + 4 * q) = hi;
    }

    bf16x8 hf = *reinterpret_cast<bf16x8*>(&hlds[row * 40 + q * 8]);
    bf16x8 spf;
    {
        const float* sp = spatial_in + (size_t)(base + row) * 32 + 8 * q;
        #pragma unroll
        for (int i = 0; i < 8; i++) spf[i] = (__bf16)sp[i];
    }

    #pragma unroll
    for (int T = 0; T < 4; T++) {
        bf16x8 x0 = ldfrag(fc1w + (size_t)(16 * T + row) * 64 + 8 * q);
        bf16x8 x1 = ldfrag(fc1w + (size_t)(16 * T + row) * 64 + 32 + 8 * q);
        f32x4 c;
        #pragma unroll
        for (int i = 0; i < 4; i++) c[i] = fc1b[16 * T + 4 * q + i];
        f32x4 a = __builtin_amdgcn_mfma_f32_16x16x32_bf16(x0, hf,  c, 0, 0, 0);
        a       = __builtin_amdgcn_mfma_f32_16x16x32_bf16(x1, spf, a, 0, 0, 0);
        bf16x4 zv;
        #pragma unroll
        for (int i = 0; i < 4; i++) zv[i] = (__bf16)fmaxf(a[i], 0.f);
        *reinterpret_cast<bf16x4*>(&zlds[row * 72 + 16 * T + 4 * q]) = zv;
    }
    bf16x8 z1f0 = *reinterpret_cast<bf16x8*>(&zlds[row * 72 + 8 * q]);
    bf16x8 z1f1 = *reinterpret_cast<bf16x8*>(&zlds[row * 72 + 32 + 8 * q]);

    #pragma unroll
    for (int T = 0; T < 2; T++) {
        bf16x8 x0 = ldfrag(fc2w + (size_t)(16 * T + row) * 64 + 8 * q);
        bf16x8 x1 = ldfrag(fc2w + (size_t)(16 * T + row) * 64 + 32 + 8 * q);
        f32x4 c;
        #pragma unroll
        for (int i = 0; i < 4; i++) c[i] = fc2b[16 * T + 4 * q + i];
        f32x4 a = __builtin_amdgcn_mfma_f32_16x16x32_bf16(x0, z1f0, c, 0, 0, 0);
        a       = __builtin_amdgcn_mfma_f32_16x16x32_bf16(x1, z1f1, a, 0, 0, 0);
        bf16x4 zv;
        #pragma unroll
        for (int i = 0; i < 4; i++) zv[i] = (__bf16)fmaxf(a[i], 0.f);
        *reinterpret_cast<bf16x4*>(&hlds[row * 40 + 16 * T + 4 * q]) = zv;
    }
    bf16x8 z2f = *reinterpret_cast<bf16x8*>(&hlds[row * 40 + 8 * q]);

    {
        bf16x8 x3 = ldfrag(fc3w + (size_t)(row & 3) * 32 + 8 * q);
        f32x4 c;
        #pragma unroll
        for (int i = 0; i < 4; i++) c[i] = fc3b[i];
        f32x4 o = __builtin_amdgcn_mfma_f32_16x16x32_bf16(x3, z2f, c, 0, 0, 0);
        if (l < 16)
            *reinterpret_cast<f32x4*>(out0 + (size_t)(base + row) * 4) = o;
    }
}

// ---------------------------------------------------------------------------
extern "C" void kernel_launch(void* const* d_in, const int* in_sizes, int n_in,
                              void* d_out, int out_size, void* d_ws, size_t ws_size,
                              hipStream_t stream) {
    const float* x    = (const float*)d_in[0];
    const float* w1   = (const float*)d_in[1];
    const float* b1   = (const float*)d_in[2];
    const float* g1   = (const float*)d_in[3];
    const float* be1  = (const float*)d_in[4];
    const float* m1   = (const float*)d_in[5];
    const float* v1   = (const float*)d_in[6];
    const float* w2   = (const float*)d_in[7];
    const float* b2   = (const float*)d_in[8];
    const float* g2   = (const float*)d_in[9];
    const float* be2  = (const float*)d_in[10];
    const float* m2   = (const float*)d_in[11];
    const float* v2   = (const float*)d_in[12];
    const float* w3   = (const float*)d_in[13];
    const float* b3   = (const float*)d_in[14];
    const float* g3   = (const float*)d_in[15];
    const float* be3  = (const float*)d_in[16];
    const float* m3   = (const float*)d_in[17];
    const float* v3   = (const float*)d_in[18];
    const float* w_ih = (const float*)d_in[19];
    const float* w_hh = (const float*)d_in[20];
    const float* b_ih = (const float*)d_in[21];
    const float* b_hh = (const float*)d_in[22];
    const float* fc1w = (const float*)d_in[23];
    const float* fc1b = (const float*)d_in[24];
    const float* fc2w = (const float*)d_in[25];
    const float* fc2b = (const float*)d_in[26];
    const float* fc3w = (const float*)d_in[27];
    const float* fc3b = (const float*)d_in[28];

    float* out0    = (float*)d_out;                 // [8192][4]
    float* spatial = out0 + (size_t)NB * 4;         // [8192][32]
    float* hlast   = spatial + (size_t)NB * 32;     // [8192][32]
    unsigned int* spk = (unsigned int*)d_ws;        // [8192][32] bitmasks
    float* wsf = (float*)d_ws + WSF_OFF;            // folded weights (9.2 KB)

    hipLaunchKernelGGL(fold_kernel, dim3(9), dim3(256), 0, stream,
                       w1, b1, g1, be1, m1, v1,
                       w2, b2, g2, be2, m2, v2,
                       w3, b3, g3, be3, m3, v3, wsf);

    hipLaunchKernelGGL(conv_lif_kernel, dim3(NB), dim3(256), 0, stream,
                       x, wsf, spatial, spk);

    hipLaunchKernelGGL(lstm_fc_mfma_kernel, dim3(NB / 16), dim3(64), 0, stream,
                       spk, w_ih, w_hh, b_ih, b_hh,
                       fc1w, fc1b, fc2w, fc2b, fc3w, fc3b,
                       spatial, out0, hlast);
}

// Round 8
// 82.757 us; speedup vs baseline: 1.1729x; 1.0366x over previous
//
#include <hip/hip_runtime.h>

#define NB 8192
#define EPS_BN 1e-5f

// padded LDS index: +4 floats every 32 => stride-16B lane patterns are
// conflict-free while float4/float2 alignment is preserved (4 | pad).
#define PADX(i) ((i) + ((((i) >> 5)) << 2))

using bf16x8 = __attribute__((ext_vector_type(8))) __bf16;
using bf16x4 = __attribute__((ext_vector_type(4))) __bf16;
using f32x4  = __attribute__((ext_vector_type(4))) float;
using f32x2  = __attribute__((ext_vector_type(2))) float;

// folded-weight layout in d_ws (float offsets, after 1MB spk region):
//   0    wA1[64]   [k:8][c:8] (k<7 valid)
//   64   bA1[8]
//   80   wB2[640]  [(ci*5+k)*16 + c]
//   720  bB2[16]
//   736  wC3[1536] [(ci*3+k)*32 + c]
//   2272 bC3[32]
#define WSF_OFF   262144           // floats: spk = 8192*32 uints = 1MB

// ---------------------------------------------------------------------------
// Kernel 0: fold BN into conv weights once (UNCHANGED from round 7).
// ---------------------------------------------------------------------------
__global__ __launch_bounds__(256) void fold_kernel(
    const float* __restrict__ w1, const float* __restrict__ b1,
    const float* __restrict__ g1, const float* __restrict__ be1,
    const float* __restrict__ m1, const float* __restrict__ v1,
    const float* __restrict__ w2, const float* __restrict__ b2,
    const float* __restrict__ g2, const float* __restrict__ be2,
    const float* __restrict__ m2, const float* __restrict__ v2,
    const float* __restrict__ w3, const float* __restrict__ b3,
    const float* __restrict__ g3, const float* __restrict__ be3,
    const float* __restrict__ m3, const float* __restrict__ v3,
    float* __restrict__ wsf)
{
    int j = blockIdx.x * 256 + threadIdx.x;
    if (j < 64) {
        int k = j >> 3, c = j & 7;
        wsf[j] = (k < 7) ? w1[c * 7 + k] * (g1[c] * rsqrtf(v1[c] + EPS_BN)) : 0.f;
    } else if (j < 72) {
        int c = j - 64;
        float inv = g1[c] * rsqrtf(v1[c] + EPS_BN);
        wsf[j] = (b1[c] - m1[c]) * inv + be1[c];
    } else if (j >= 80 && j < 720) {
        int i = j - 80, c = i & 15, t = i >> 4, ci = t / 5, k = t - 5 * ci;
        wsf[j] = w2[(c * 8 + ci) * 5 + k] * (g2[c] * rsqrtf(v2[c] + EPS_BN));
    } else if (j >= 720 && j < 736) {
        int c = j - 720;
        float inv = g2[c] * rsqrtf(v2[c] + EPS_BN);
        wsf[j] = (b2[c] - m2[c]) * inv + be2[c];
    } else if (j >= 736 && j < 2272) {
        int i = j - 736, c = i & 31, t = i >> 5, ci = t / 3, k = t - 3 * ci;
        wsf[j] = w3[(c * 16 + ci) * 3 + k] * (g3[c] * rsqrtf(v3[c] + EPS_BN));
    } else if (j >= 2272 && j < 2304) {
        int c = j - 2272;
        float inv = g3[c] * rsqrtf(v3[c] + EPS_BN);
        wsf[j] = (b3[c] - m3[c]) * inv + be3[c];
    }
}

// ---------------------------------------------------------------------------
// Kernel 1: conv stack + LIF. One block (256 thr) = TWO batch elements.
// Every phase uses all 4 waves; channel-group is WAVE-UNIFORM so folded
// weights come via scalar s_load broadcast (no LDS/VALU cost); window data
// from padded LDS tiles; pk-FMA pairs over channels; no duplicated work.
// Per-output accumulation order: ci-major, k-minor (unchanged since round 2).
// LIF: full wave = 2 batches x 32 ch; ballot lo/hi = the two spike words.
// ---------------------------------------------------------------------------
__device__ inline f32x2 pkfma(f32x2 a, f32x2 b, f32x2 c) {
    return __builtin_elementwise_fma(a, b, c);
}

__global__ __launch_bounds__(256) void conv_lif_kernel(
    const float* __restrict__ x,
    const float* __restrict__ wsf,          // folded weights (global, s_load)
    float* __restrict__ spatial_out,        // [B][32]
    unsigned int* __restrict__ spk)         // [B][32] bitmask per (b,t)
{
    __shared__ alignas(16) float xs[2][1168];   // [8 zero | 1024 | 8 zero] PADX'd
    __shared__ alignas(16) float c1s[2][2336];  // 8 rows x 292, idx pos+2 PADX'd
    __shared__ alignas(16) float c2s[2][1216];  // 16 rows x 76, idx pos+1 PADX'd
    __shared__ alignas(16) float c3s[2][1056];  // 32 rows x 33 (+1 pad)

    const int b0  = blockIdx.x * 2;
    const int tid = threadIdx.x;

    // ---- zero pads + stage x (both batch elements) ----
    if (tid < 16) {
        int be = tid >> 3, j = tid & 7;
        xs[be][j] = 0.f;
        xs[be][PADX(1032 + j)] = 0.f;
    } else if (tid >= 32 && tid < 64) {
        int j = tid - 32;                   // 2 be x 8 rows x 2 front zeros
        c1s[j >> 4][((j >> 1) & 7) * 292 + (j & 1)] = 0.f;
    } else if (tid >= 64 && tid < 96) {
        int j = tid - 64;                   // 2 be x 16 rows front zeros
        c2s[j >> 4][(j & 15) * 76] = 0.f;
    }
    {
        float4 xv0 = reinterpret_cast<const float4*>(x + (size_t)b0 * 1024)[tid];
        *reinterpret_cast<float4*>(&xs[0][PADX(8 + 4 * tid)]) = xv0;
        float4 xv1 = reinterpret_cast<const float4*>(x + (size_t)(b0 + 1) * 1024)[tid];
        *reinterpret_cast<float4*>(&xs[1][PADX(8 + 4 * tid)]) = xv1;
    }
    __syncthreads();

    // ---- conv1: thread = position (256), both be, 8 ch as 4 pk-pairs ----
    {
        const int t    = tid;
        const int base = 4 * t + 4;
        #pragma unroll
        for (int be = 0; be < 2; be++) {
            float4 xa = *reinterpret_cast<const float4*>(&xs[be][PADX(base)]);
            float4 xb = *reinterpret_cast<const float4*>(&xs[be][PADX(base + 4)]);
            float win[7] = {xa.y, xa.z, xa.w, xb.x, xb.y, xb.z, xb.w};
            #pragma unroll
            for (int cp = 0; cp < 4; cp++) {
                f32x2 acc = *reinterpret_cast<const f32x2*>(wsf + 64 + 2 * cp);
                #pragma unroll
                for (int k = 0; k < 7; k++) {
                    f32x2 wv = *reinterpret_cast<const f32x2*>(wsf + k * 8 + 2 * cp);
                    f32x2 sv = {win[k], win[k]};
                    acc = pkfma(wv, sv, acc);
                }
                c1s[be][(2 * cp + 0) * 292 + PADX(2 + t)] = fmaxf(acc[0], 0.f);
                c1s[be][(2 * cp + 1) * 292 + PADX(2 + t)] = fmaxf(acc[1], 0.f);
            }
        }
    }
    __syncthreads();

    // ---- conv2: thread = (be,pos) = tid&127, ch-oct = (tid>>7)*8 ----
    // waves 0,1 -> ch 0-7 (be0,be1); waves 2,3 -> ch 8-15. cb wave-uniform.
    {
        const int p2  = tid & 127;
        const int be  = p2 >> 6;
        const int pos = p2 & 63;
        const int cb  = __builtin_amdgcn_readfirstlane(tid >> 7) << 3;  // 0 or 8
        const float* wB2 = wsf + 80;
        const float* bB2 = wsf + 720;
        f32x2 a01 = *reinterpret_cast<const f32x2*>(bB2 + cb);
        f32x2 a23 = *reinterpret_cast<const f32x2*>(bB2 + cb + 2);
        f32x2 a45 = *reinterpret_cast<const f32x2*>(bB2 + cb + 4);
        f32x2 a67 = *reinterpret_cast<const f32x2*>(bB2 + cb + 6);
        const float* c1t = c1s[be];
        #pragma unroll
        for (int ci = 0; ci < 8; ci++) {
            const float* row = c1t + ci * 292;
            float4 va = *reinterpret_cast<const float4*>(&row[PADX(4 * pos)]);
            float  v4 = row[PADX(4 * pos + 4)];
            float win[5] = {va.x, va.y, va.z, va.w, v4};
            #pragma unroll
            for (int k = 0; k < 5; k++) {
                const float* wp = wB2 + (ci * 5 + k) * 16 + cb;   // uniform -> s_load
                f32x2 sv = {win[k], win[k]};
                a01 = pkfma(*reinterpret_cast<const f32x2*>(wp),     sv, a01);
                a23 = pkfma(*reinterpret_cast<const f32x2*>(wp + 2), sv, a23);
                a45 = pkfma(*reinterpret_cast<const f32x2*>(wp + 4), sv, a45);
                a67 = pkfma(*reinterpret_cast<const f32x2*>(wp + 6), sv, a67);
            }
        }
        float* c2t = c2s[be];
        c2t[(cb + 0) * 76 + PADX(1 + pos)] = fmaxf(a01[0], 0.f);
        c2t[(cb + 1) * 76 + PADX(1 + pos)] = fmaxf(a01[1], 0.f);
        c2t[(cb + 2) * 76 + PADX(1 + pos)] = fmaxf(a23[0], 0.f);
        c2t[(cb + 3) * 76 + PADX(1 + pos)] = fmaxf(a23[1], 0.f);
        c2t[(cb + 4) * 76 + PADX(1 + pos)] = fmaxf(a45[0], 0.f);
        c2t[(cb + 5) * 76 + PADX(1 + pos)] = fmaxf(a45[1], 0.f);
        c2t[(cb + 6) * 76 + PADX(1 + pos)] = fmaxf(a67[0], 0.f);
        c2t[(cb + 7) * 76 + PADX(1 + pos)] = fmaxf(a67[1], 0.f);
    }
    __syncthreads();

    // ---- conv3: thread = (be,pos) = tid&63, ch-oct = (tid>>6)*8 ----
    // wave w -> ch 8w..8w+7 (uniform); lanes 0-31 be0, 32-63 be1.
    {
        const int pl  = tid & 63;
        const int be  = pl >> 5;
        const int pos = pl & 31;
        const int cb  = __builtin_amdgcn_readfirstlane(tid >> 6) << 3;  // 0,8,16,24
        const float* wC3 = wsf + 736;
        const float* bC3 = wsf + 2272;
        f32x2 a01 = *reinterpret_cast<const f32x2*>(bC3 + cb);
        f32x2 a23 = *reinterpret_cast<const f32x2*>(bC3 + cb + 2);
        f32x2 a45 = *reinterpret_cast<const f32x2*>(bC3 + cb + 4);
        f32x2 a67 = *reinterpret_cast<const f32x2*>(bC3 + cb + 6);
        const float* c2t = c2s[be];
        #pragma unroll
        for (int ci = 0; ci < 16; ci++) {
            const float* row = c2t + ci * 76;
            float2 vab = *reinterpret_cast<const float2*>(&row[PADX(2 * pos)]);
            float  vc  = row[PADX(2 * pos + 2)];
            float win[3] = {vab.x, vab.y, vc};
            #pragma unroll
            for (int k = 0; k < 3; k++) {
                const float* wp = wC3 + (ci * 3 + k) * 32 + cb;   // uniform -> s_load
                f32x2 sv = {win[k], win[k]};
                a01 = pkfma(*reinterpret_cast<const f32x2*>(wp),     sv, a01);
                a23 = pkfma(*reinterpret_cast<const f32x2*>(wp + 2), sv, a23);
                a45 = pkfma(*reinterpret_cast<const f32x2*>(wp + 4), sv, a45);
                a67 = pkfma(*reinterpret_cast<const f32x2*>(wp + 6), sv, a67);
            }
        }
        float* c3t = c3s[be];
        c3t[(cb + 0) * 33 + pos] = fmaxf(a01[0], 0.f);
        c3t[(cb + 1) * 33 + pos] = fmaxf(a01[1], 0.f);
        c3t[(cb + 2) * 33 + pos] = fmaxf(a23[0], 0.f);
        c3t[(cb + 3) * 33 + pos] = fmaxf(a23[1], 0.f);
        c3t[(cb + 4) * 33 + pos] = fmaxf(a45[0], 0.f);
        c3t[(cb + 5) * 33 + pos] = fmaxf(a45[1], 0.f);
        c3t[(cb + 6) * 33 + pos] = fmaxf(a67[0], 0.f);
        c3t[(cb + 7) * 33 + pos] = fmaxf(a67[1], 0.f);
    }
    __syncthreads();

    // ---- spatial mean + LIF: full wave 0 = 2 batches x 32 channels ----
    if (tid < 64) {
        const int be = tid >> 5, ch = tid & 31;
        const float* c3t = c3s[be];
        float s = 0.f;
        #pragma unroll
        for (int t = 0; t < 32; t++) s += c3t[ch * 33 + t];
        spatial_out[(size_t)(b0 + be) * 32 + ch] = s * 0.03125f;

        float mem = 0.f;
        #pragma unroll
        for (int t = 0; t < 32; t++) {
            mem = __fadd_rn(__fmul_rn(0.9f, mem), c3t[ch * 33 + t]);
            bool spike = mem > 0.5f;
            mem = spike ? 0.f : mem;
            unsigned long long msk = __ballot(spike);
            if (tid == 0) {
                spk[(size_t)b0 * 32 + t]      = (unsigned int)(msk & 0xffffffffull);
                spk[(size_t)b0 * 32 + 32 + t] = (unsigned int)(msk >> 32);
            }
        }
    }
}

// ---------------------------------------------------------------------------
// Kernel 2: MFMA-batched LSTM + FC head (UNCHANGED from round 5).
// ---------------------------------------------------------------------------
__device__ inline float sigm(float x) {
    return __builtin_amdgcn_rcpf(1.f + __expf(-x));
}
__device__ inline float tanh_(float x) {
    return fmaf(2.f, __builtin_amdgcn_rcpf(1.f + __expf(-2.f * x)), -1.f);
}
__device__ inline bf16x8 ldfrag(const float* __restrict__ p) {
    bf16x8 r;
    #pragma unroll
    for (int i = 0; i < 8; i++) r[i] = (__bf16)p[i];
    return r;
}

__global__ __launch_bounds__(64, 2) void lstm_fc_mfma_kernel(
    const unsigned int* __restrict__ spk,   // [B][32]
    const float* __restrict__ w_ih, const float* __restrict__ w_hh,
    const float* __restrict__ b_ih, const float* __restrict__ b_hh,
    const float* __restrict__ fc1w, const float* __restrict__ fc1b,
    const float* __restrict__ fc2w, const float* __restrict__ fc2b,
    const float* __restrict__ fc3w, const float* __restrict__ fc3b,
    const float* __restrict__ spatial_in,   // [B][32]
    float* __restrict__ out0,               // [B][4]
    float* __restrict__ hlast_out)          // [B][32]
{
    const int l    = threadIdx.x;
    const int row  = l & 15;                // batch-within-tile (and X gate-row)
    const int q    = l >> 4;                // k-group 0..3
    const int base = blockIdx.x * 16;

    __shared__ unsigned int mlds[512];      // [t][16] spike masks
    __shared__ __bf16 hlds[640];            // [16][40]
    __shared__ __bf16 zlds[1152];           // [16][72]

    for (int i = l; i < 512; i += 64) {
        int j = i >> 5, t = i & 31;
        mlds[t * 16 + j] = spk[(size_t)(base + j) * 32 + t];
    }
    for (int i = l; i < 640; i += 64) hlds[i] = (__bf16)0.f;

    bf16x8 wih[8], whh[8];
    f32x4  bfr[8];
    #pragma unroll
    for (int T = 0; T < 8; T++) {
        wih[T] = ldfrag(w_ih + (size_t)(16 * T + row) * 32 + 8 * q);
        whh[T] = ldfrag(w_hh + (size_t)(16 * T + row) * 32 + 8 * q);
        const float* ba = b_ih + 16 * T + 4 * q;
        const float* bb = b_hh + 16 * T + 4 * q;
        f32x4 bf;
        #pragma unroll
        for (int i = 0; i < 4; i++) bf[i] = ba[i] + bb[i];
        bfr[T] = bf;
    }

    float cst[8];
    float hq[8];
    #pragma unroll
    for (int i = 0; i < 8; i++) { cst[i] = 0.f; hq[i] = 0.f; }

    #pragma unroll 1
    for (int t = 0; t < 32; t++) {
        unsigned int m  = mlds[t * 16 + row];
        unsigned int by = (m >> (q * 8)) & 0xFFu;
        union { bf16x8 v; unsigned int u[4]; } a1;
        a1.u[0] = ((by & 1u)        * 0x3F80u) | (((by >> 1) & 1u) * 0x3F800000u);
        a1.u[1] = (((by >> 2) & 1u) * 0x3F80u) | (((by >> 3) & 1u) * 0x3F800000u);
        a1.u[2] = (((by >> 4) & 1u) * 0x3F80u) | (((by >> 5) & 1u) * 0x3F800000u);
        a1.u[3] = (((by >> 6) & 1u) * 0x3F80u) | (((by >> 7) & 1u) * 0x3F800000u);
        bf16x8 a2 = *reinterpret_cast<bf16x8*>(&hlds[row * 40 + q * 8]);

        f32x4 acc[8];
        #pragma unroll
        for (int T = 0; T < 8; T++) {
            acc[T] = __builtin_amdgcn_mfma_f32_16x16x32_bf16(wih[T], a1.v, bfr[T], 0, 0, 0);
            acc[T] = __builtin_amdgcn_mfma_f32_16x16x32_bf16(whh[T], a2,   acc[T], 0, 0, 0);
        }

        #pragma unroll
        for (int j = 0; j < 4; j++) {
            float iv = sigm(acc[0][j]);
            float fv = sigm(acc[2][j]);
            float gv = tanh_(acc[4][j]);
            float ov = sigm(acc[6][j]);
            cst[j] = fmaf(fv, cst[j], iv * gv);
            hq[j]  = ov * tanh_(cst[j]);
            float iv2 = sigm(acc[1][j]);
            float fv2 = sigm(acc[3][j]);
            float gv2 = tanh_(acc[5][j]);
            float ov2 = sigm(acc[7][j]);
            cst[4 + j] = fmaf(fv2, cst[4 + j], iv2 * gv2);
            hq[4 + j]  = ov2 * tanh_(cst[4 + j]);
        }

        bf16x4 hv0, hv1;
        #pragma unroll
        for (int j = 0; j < 4; j++) { hv0[j] = (__bf16)hq[j]; hv1[j] = (__bf16)hq[4 + j]; }
        *reinterpret_cast<bf16x4*>(&hlds[row * 40 + 4 * q])      = hv0;
        *reinterpret_cast<bf16x4*>(&hlds[row * 40 + 16 + 4 * q]) = hv1;
    }

    {
        f32x4 lo, hi;
        #pragma unroll
        for (int j = 0; j < 4; j++) { lo[j] = hq[j]; hi[j] = hq[4 + j]; }
        *reinterpret_cast<f32x4*>(hlast_out + (size_t)(base + row) * 32 + 4 * q)      = lo;
        *reinterpret_cast<f32x4*>(hlast_out + (size_t)(base + row) * 32 + 16 + 4 * q) = hi;
    }

    bf16x8 hf = *reinterpret_cast<bf16x8*>(&hlds[row * 40 + q * 8]);
    bf16x8 spf;
    {
        const float* sp = spatial_in + (size_t)(base + row) * 32 + 8 * q;
        #pragma unroll
        for (int i = 0; i < 8; i++) spf[i] = (__bf16)sp[i];
    }

    #pragma unroll
    for (int T = 0; T < 4; T++) {
        bf16x8 x0 = ldfrag(fc1w + (size_t)(16 * T + row) * 64 + 8 * q);
        bf16x8 x1 = ldfrag(fc1w + (size_t)(16 * T + row) * 64 + 32 + 8 * q);
        f32x4 c;
        #pragma unroll
        for (int i = 0; i < 4; i++) c[i] = fc1b[16 * T + 4 * q + i];
        f32x4 a = __builtin_amdgcn_mfma_f32_16x16x32_bf16(x0, hf,  c, 0, 0, 0);
        a       = __builtin_amdgcn_mfma_f32_16x16x32_bf16(x1, spf, a, 0, 0, 0);
        bf16x4 zv;
        #pragma unroll
        for (int i = 0; i < 4; i++) zv[i] = (__bf16)fmaxf(a[i], 0.f);
        *reinterpret_cast<bf16x4*>(&zlds[row * 72 + 16 * T + 4 * q]) = zv;
    }
    bf16x8 z1f0 = *reinterpret_cast<bf16x8*>(&zlds[row * 72 + 8 * q]);
    bf16x8 z1f1 = *reinterpret_cast<bf16x8*>(&zlds[row * 72 + 32 + 8 * q]);

    #pragma unroll
    for (int T = 0; T < 2; T++) {
        bf16x8 x0 = ldfrag(fc2w + (size_t)(16 * T + row) * 64 + 8 * q);
        bf16x8 x1 = ldfrag(fc2w + (size_t)(16 * T + row) * 64 + 32 + 8 * q);
        f32x4 c;
        #pragma unroll
        for (int i = 0; i < 4; i++) c[i] = fc2b[16 * T + 4 * q + i];
        f32x4 a = __builtin_amdgcn_mfma_f32_16x16x32_bf16(x0, z1f0, c, 0, 0, 0);
        a       = __builtin_amdgcn_mfma_f32_16x16x32_bf16(x1, z1f1, a, 0, 0, 0);
        bf16x4 zv;
        #pragma unroll
        for (int i = 0; i < 4; i++) zv[i] = (__bf16)fmaxf(a[i], 0.f);
        *reinterpret_cast<bf16x4*>(&hlds[row * 40 + 16 * T + 4 * q]) = zv;
    }
    bf16x8 z2f = *reinterpret_cast<bf16x8*>(&hlds[row * 40 + 8 * q]);

    {
        bf16x8 x3 = ldfrag(fc3w + (size_t)(row & 3) * 32 + 8 * q);
        f32x4 c;
        #pragma unroll
        for (int i = 0; i < 4; i++) c[i] = fc3b[i];
        f32x4 o = __builtin_amdgcn_mfma_f32_16x16x32_bf16(x3, z2f, c, 0, 0, 0);
        if (l < 16)
            *reinterpret_cast<f32x4*>(out0 + (size_t)(base + row) * 4) = o;
    }
}

// ---------------------------------------------------------------------------
extern "C" void kernel_launch(void* const* d_in, const int* in_sizes, int n_in,
                              void* d_out, int out_size, void* d_ws, size_t ws_size,
                              hipStream_t stream) {
    const float* x    = (const float*)d_in[0];
    const float* w1   = (const float*)d_in[1];
    const float* b1   = (const float*)d_in[2];
    const float* g1   = (const float*)d_in[3];
    const float* be1  = (const float*)d_in[4];
    const float* m1   = (const float*)d_in[5];
    const float* v1   = (const float*)d_in[6];
    const float* w2   = (const float*)d_in[7];
    const float* b2   = (const float*)d_in[8];
    const float* g2   = (const float*)d_in[9];
    const float* be2  = (const float*)d_in[10];
    const float* m2   = (const float*)d_in[11];
    const float* v2   = (const float*)d_in[12];
    const float* w3   = (const float*)d_in[13];
    const float* b3   = (const float*)d_in[14];
    const float* g3   = (const float*)d_in[15];
    const float* be3  = (const float*)d_in[16];
    const float* m3   = (const float*)d_in[17];
    const float* v3   = (const float*)d_in[18];
    const float* w_ih = (const float*)d_in[19];
    const float* w_hh = (const float*)d_in[20];
    const float* b_ih = (const float*)d_in[21];
    const float* b_hh = (const float*)d_in[22];
    const float* fc1w = (const float*)d_in[23];
    const float* fc1b = (const float*)d_in[24];
    const float* fc2w = (const float*)d_in[25];
    const float* fc2b = (const float*)d_in[26];
    const float* fc3w = (const float*)d_in[27];
    const float* fc3b = (const float*)d_in[28];

    float* out0    = (float*)d_out;                 // [8192][4]
    float* spatial = out0 + (size_t)NB * 4;         // [8192][32]
    float* hlast   = spatial + (size_t)NB * 32;     // [8192][32]
    unsigned int* spk = (unsigned int*)d_ws;        // [8192][32] bitmasks
    float* wsf = (float*)d_ws + WSF_OFF;            // folded weights (9.2 KB)

    hipLaunchKernelGGL(fold_kernel, dim3(9), dim3(256), 0, stream,
                       w1, b1, g1, be1, m1, v1,
                       w2, b2, g2, be2, m2, v2,
                       w3, b3, g3, be3, m3, v3, wsf);

    hipLaunchKernelGGL(conv_lif_kernel, dim3(NB / 2), dim3(256), 0, stream,
                       x, wsf, spatial, spk);

    hipLaunchKernelGGL(lstm_fc_mfma_kernel, dim3(NB / 16), dim3(64), 0, stream,
                       spk, w_ih, w_hh, b_ih, b_hh,
                       fc1w, fc1b, fc2w, fc2b, fc3w, fc3b,
                       spatial, out0, hlast);
}

// Round 9
// 72.937 us; speedup vs baseline: 1.3308x; 1.1346x over previous
//
#include <hip/hip_runtime.h>

#define NB 8192
#define EPS_BN 1e-5f

// padded LDS index: +4 floats every 32 => stride-16B lane patterns are
// conflict-free while float4/float2 alignment is preserved (4 | pad).
#define PADX(i) ((i) + ((((i) >> 5)) << 2))

using bf16x8 = __attribute__((ext_vector_type(8))) __bf16;
using bf16x4 = __attribute__((ext_vector_type(4))) __bf16;
using f32x4  = __attribute__((ext_vector_type(4))) float;
using f32x2  = __attribute__((ext_vector_type(2))) float;

// folded-weight layout in d_ws (float offsets, after 1MB spk region):
//   0 wA1[64] | 64 bA1[8] | 80 wB2[640] | 720 bB2[16] | 736 wC3[1536] | 2272 bC3[32]
#define WSF_OFF   262144           // floats: spk = 8192*32 uints = 1MB

// ---------------------------------------------------------------------------
// Kernel 0: fold BN into conv weights once (UNCHANGED).
// ---------------------------------------------------------------------------
__global__ __launch_bounds__(256) void fold_kernel(
    const float* __restrict__ w1, const float* __restrict__ b1,
    const float* __restrict__ g1, const float* __restrict__ be1,
    const float* __restrict__ m1, const float* __restrict__ v1,
    const float* __restrict__ w2, const float* __restrict__ b2,
    const float* __restrict__ g2, const float* __restrict__ be2,
    const float* __restrict__ m2, const float* __restrict__ v2,
    const float* __restrict__ w3, const float* __restrict__ b3,
    const float* __restrict__ g3, const float* __restrict__ be3,
    const float* __restrict__ m3, const float* __restrict__ v3,
    float* __restrict__ wsf)
{
    int j = blockIdx.x * 256 + threadIdx.x;
    if (j < 64) {
        int k = j >> 3, c = j & 7;
        wsf[j] = (k < 7) ? w1[c * 7 + k] * (g1[c] * rsqrtf(v1[c] + EPS_BN)) : 0.f;
    } else if (j < 72) {
        int c = j - 64;
        float inv = g1[c] * rsqrtf(v1[c] + EPS_BN);
        wsf[j] = (b1[c] - m1[c]) * inv + be1[c];
    } else if (j >= 80 && j < 720) {
        int i = j - 80, c = i & 15, t = i >> 4, ci = t / 5, k = t - 5 * ci;
        wsf[j] = w2[(c * 8 + ci) * 5 + k] * (g2[c] * rsqrtf(v2[c] + EPS_BN));
    } else if (j >= 720 && j < 736) {
        int c = j - 720;
        float inv = g2[c] * rsqrtf(v2[c] + EPS_BN);
        wsf[j] = (b2[c] - m2[c]) * inv + be2[c];
    } else if (j >= 736 && j < 2272) {
        int i = j - 736, c = i & 31, t = i >> 5, ci = t / 3, k = t - 3 * ci;
        wsf[j] = w3[(c * 16 + ci) * 3 + k] * (g3[c] * rsqrtf(v3[c] + EPS_BN));
    } else if (j >= 2272 && j < 2304) {
        int c = j - 2272;
        float inv = g3[c] * rsqrtf(v3[c] + EPS_BN);
        wsf[j] = (b3[c] - m3[c]) * inv + be3[c];
    }
}

// ---------------------------------------------------------------------------
// Kernel 1: conv stack + LIF. One block (256 thr) = TWO batch elements.
// Round-8 structure + LDS LIFETIME ALIASING: {c1,c3} share region1, {xs,c2}
// share region2 -> 28.4 KB total -> 5 blocks/CU (was 46.6 KB / 3 blocks).
// Lifetimes: xs [stage,conv1] / c1 [conv1,conv2] / c2 [conv2,conv3] /
// c3 [conv3,LIF]; barriers separate phases. c2 front-zeros written in the
// conv2 phase (c2 aliases live xs during staging).
// ---------------------------------------------------------------------------
__device__ inline f32x2 pkfma(f32x2 a, f32x2 b, f32x2 c) {
    return __builtin_elementwise_fma(a, b, c);
}

__global__ __launch_bounds__(256) void conv_lif_kernel(
    const float* __restrict__ x,
    const float* __restrict__ wsf,          // folded weights (global, s_load)
    float* __restrict__ spatial_out,        // [B][32]
    unsigned int* __restrict__ spk)         // [B][32] bitmask per (b,t)
{
    // region1 floats [0,4672): c1s[be]=+be*2336 (8x292)  ALIAS c3s[be]=+be*1056 (32x33)
    // region2 floats [4672,7104): xs[be]=+be*1168        ALIAS c2s[be]=+be*1216 (16x76)
    __shared__ alignas(16) float smem[7104];
    float* const c1sb = smem;
    float* const c3sb = smem;
    float* const xsb  = smem + 4672;
    float* const c2sb = smem + 4672;

    const int b0  = blockIdx.x * 2;
    const int tid = threadIdx.x;

    // ---- zero pads (xs + c1 front) + stage x ----
    if (tid < 16) {
        int be = tid >> 3, j = tid & 7;
        float* xst = xsb + be * 1168;
        xst[j] = 0.f;
        xst[PADX(1032 + j)] = 0.f;
    } else if (tid >= 32 && tid < 64) {
        int j = tid - 32;                   // 2 be x 8 rows x 2 front zeros
        c1sb[(j >> 4) * 2336 + ((j >> 1) & 7) * 292 + (j & 1)] = 0.f;
    }
    {
        float4 xv0 = reinterpret_cast<const float4*>(x + (size_t)b0 * 1024)[tid];
        *reinterpret_cast<float4*>(&xsb[PADX(8 + 4 * tid)]) = xv0;
        float4 xv1 = reinterpret_cast<const float4*>(x + (size_t)(b0 + 1) * 1024)[tid];
        *reinterpret_cast<float4*>(&xsb[1168 + PADX(8 + 4 * tid)]) = xv1;
    }
    __syncthreads();

    // ---- conv1: thread = position (256), both be, 8 ch as 4 pk-pairs ----
    {
        const int t    = tid;
        const int base = 4 * t + 4;
        #pragma unroll
        for (int be = 0; be < 2; be++) {
            const float* xst = xsb + be * 1168;
            float* c1t = c1sb + be * 2336;
            float4 xa = *reinterpret_cast<const float4*>(&xst[PADX(base)]);
            float4 xb = *reinterpret_cast<const float4*>(&xst[PADX(base + 4)]);
            float win[7] = {xa.y, xa.z, xa.w, xb.x, xb.y, xb.z, xb.w};
            #pragma unroll
            for (int cp = 0; cp < 4; cp++) {
                f32x2 acc = *reinterpret_cast<const f32x2*>(wsf + 64 + 2 * cp);
                #pragma unroll
                for (int k = 0; k < 7; k++) {
                    f32x2 wv = *reinterpret_cast<const f32x2*>(wsf + k * 8 + 2 * cp);
                    f32x2 sv = {win[k], win[k]};
                    acc = pkfma(wv, sv, acc);
                }
                c1t[(2 * cp + 0) * 292 + PADX(2 + t)] = fmaxf(acc[0], 0.f);
                c1t[(2 * cp + 1) * 292 + PADX(2 + t)] = fmaxf(acc[1], 0.f);
            }
        }
    }
    __syncthreads();

    // ---- conv2: thread = (be,pos) = tid&127, ch-oct = (tid>>7)*8 ----
    {
        const int p2  = tid & 127;
        const int be  = p2 >> 6;
        const int pos = p2 & 63;
        const int cb  = __builtin_amdgcn_readfirstlane(tid >> 7) << 3;  // 0 or 8
        const float* wB2 = wsf + 80;
        const float* bB2 = wsf + 720;
        f32x2 a01 = *reinterpret_cast<const f32x2*>(bB2 + cb);
        f32x2 a23 = *reinterpret_cast<const f32x2*>(bB2 + cb + 2);
        f32x2 a45 = *reinterpret_cast<const f32x2*>(bB2 + cb + 4);
        f32x2 a67 = *reinterpret_cast<const f32x2*>(bB2 + cb + 6);
        const float* c1t = c1sb + be * 2336;
        float* c2t = c2sb + be * 1216;
        if (pos == 0) {                     // front zeros (c2 aliases dead xs)
            #pragma unroll
            for (int j = 0; j < 8; j++) c2t[(cb + j) * 76] = 0.f;
        }
        #pragma unroll
        for (int ci = 0; ci < 8; ci++) {
            const float* row = c1t + ci * 292;
            float4 va = *reinterpret_cast<const float4*>(&row[PADX(4 * pos)]);
            float  v4 = row[PADX(4 * pos + 4)];
            float win[5] = {va.x, va.y, va.z, va.w, v4};
            #pragma unroll
            for (int k = 0; k < 5; k++) {
                const float* wp = wB2 + (ci * 5 + k) * 16 + cb;   // uniform -> s_load
                f32x2 sv = {win[k], win[k]};
                a01 = pkfma(*reinterpret_cast<const f32x2*>(wp),     sv, a01);
                a23 = pkfma(*reinterpret_cast<const f32x2*>(wp + 2), sv, a23);
                a45 = pkfma(*reinterpret_cast<const f32x2*>(wp + 4), sv, a45);
                a67 = pkfma(*reinterpret_cast<const f32x2*>(wp + 6), sv, a67);
            }
        }
        c2t[(cb + 0) * 76 + PADX(1 + pos)] = fmaxf(a01[0], 0.f);
        c2t[(cb + 1) * 76 + PADX(1 + pos)] = fmaxf(a01[1], 0.f);
        c2t[(cb + 2) * 76 + PADX(1 + pos)] = fmaxf(a23[0], 0.f);
        c2t[(cb + 3) * 76 + PADX(1 + pos)] = fmaxf(a23[1], 0.f);
        c2t[(cb + 4) * 76 + PADX(1 + pos)] = fmaxf(a45[0], 0.f);
        c2t[(cb + 5) * 76 + PADX(1 + pos)] = fmaxf(a45[1], 0.f);
        c2t[(cb + 6) * 76 + PADX(1 + pos)] = fmaxf(a67[0], 0.f);
        c2t[(cb + 7) * 76 + PADX(1 + pos)] = fmaxf(a67[1], 0.f);
    }
    __syncthreads();

    // ---- conv3: thread = (be,pos) = tid&63, ch-oct = (tid>>6)*8 ----
    {
        const int pl  = tid & 63;
        const int be  = pl >> 5;
        const int pos = pl & 31;
        const int cb  = __builtin_amdgcn_readfirstlane(tid >> 6) << 3;  // 0,8,16,24
        const float* wC3 = wsf + 736;
        const float* bC3 = wsf + 2272;
        f32x2 a01 = *reinterpret_cast<const f32x2*>(bC3 + cb);
        f32x2 a23 = *reinterpret_cast<const f32x2*>(bC3 + cb + 2);
        f32x2 a45 = *reinterpret_cast<const f32x2*>(bC3 + cb + 4);
        f32x2 a67 = *reinterpret_cast<const f32x2*>(bC3 + cb + 6);
        const float* c2t = c2sb + be * 1216;
        #pragma unroll
        for (int ci = 0; ci < 16; ci++) {
            const float* row = c2t + ci * 76;
            float2 vab = *reinterpret_cast<const float2*>(&row[PADX(2 * pos)]);
            float  vc  = row[PADX(2 * pos + 2)];
            float win[3] = {vab.x, vab.y, vc};
            #pragma unroll
            for (int k = 0; k < 3; k++) {
                const float* wp = wC3 + (ci * 3 + k) * 32 + cb;   // uniform -> s_load
                f32x2 sv = {win[k], win[k]};
                a01 = pkfma(*reinterpret_cast<const f32x2*>(wp),     sv, a01);
                a23 = pkfma(*reinterpret_cast<const f32x2*>(wp + 2), sv, a23);
                a45 = pkfma(*reinterpret_cast<const f32x2*>(wp + 4), sv, a45);
                a67 = pkfma(*reinterpret_cast<const f32x2*>(wp + 6), sv, a67);
            }
        }
        float* c3t = c3sb + be * 1056;      // region1 (c1 dead)
        c3t[(cb + 0) * 33 + pos] = fmaxf(a01[0], 0.f);
        c3t[(cb + 1) * 33 + pos] = fmaxf(a01[1], 0.f);
        c3t[(cb + 2) * 33 + pos] = fmaxf(a23[0], 0.f);
        c3t[(cb + 3) * 33 + pos] = fmaxf(a23[1], 0.f);
        c3t[(cb + 4) * 33 + pos] = fmaxf(a45[0], 0.f);
        c3t[(cb + 5) * 33 + pos] = fmaxf(a45[1], 0.f);
        c3t[(cb + 6) * 33 + pos] = fmaxf(a67[0], 0.f);
        c3t[(cb + 7) * 33 + pos] = fmaxf(a67[1], 0.f);
    }
    __syncthreads();

    // ---- spatial mean + LIF: full wave 0 = 2 batches x 32 channels ----
    if (tid < 64) {
        const int be = tid >> 5, ch = tid & 31;
        const float* c3t = c3sb + be * 1056;
        float s = 0.f;
        #pragma unroll
        for (int t = 0; t < 32; t++) s += c3t[ch * 33 + t];
        spatial_out[(size_t)(b0 + be) * 32 + ch] = s * 0.03125f;

        float mem = 0.f;
        #pragma unroll
        for (int t = 0; t < 32; t++) {
            mem = __fadd_rn(__fmul_rn(0.9f, mem), c3t[ch * 33 + t]);
            bool spike = mem > 0.5f;
            mem = spike ? 0.f : mem;
            unsigned long long msk = __ballot(spike);
            if (tid == 0) {
                spk[(size_t)b0 * 32 + t]      = (unsigned int)(msk & 0xffffffffull);
                spk[(size_t)b0 * 32 + 32 + t] = (unsigned int)(msk >> 32);
            }
        }
    }
}

// ---------------------------------------------------------------------------
// Kernel 2: MFMA-batched LSTM + FC head, TWO waves per block (16 batches).
// Wave w owns gate-tiles {w, 2+w, 4+w, 6+w} = channels 16w..16w+15 of each
// gate; cell update stays lane-local (identical MFMA operands as the 1-wave
// version -> bit-identical). h exchanged via LDS, 2 barriers/step. Doubles
// wave parallelism: 1024 waves (one per SIMD).
// ---------------------------------------------------------------------------
__device__ inline float sigm(float x) {
    return __builtin_amdgcn_rcpf(1.f + __expf(-x));
}
__device__ inline float tanh_(float x) {
    return fmaf(2.f, __builtin_amdgcn_rcpf(1.f + __expf(-2.f * x)), -1.f);
}
__device__ inline bf16x8 ldfrag(const float* __restrict__ p) {
    bf16x8 r;
    #pragma unroll
    for (int i = 0; i < 8; i++) r[i] = (__bf16)p[i];
    return r;
}

__global__ __launch_bounds__(128, 2) void lstm_fc_mfma_kernel(
    const unsigned int* __restrict__ spk,   // [B][32]
    const float* __restrict__ w_ih, const float* __restrict__ w_hh,
    const float* __restrict__ b_ih, const float* __restrict__ b_hh,
    const float* __restrict__ fc1w, const float* __restrict__ fc1b,
    const float* __restrict__ fc2w, const float* __restrict__ fc2b,
    const float* __restrict__ fc3w, const float* __restrict__ fc3b,
    const float* __restrict__ spatial_in,   // [B][32]
    float* __restrict__ out0,               // [B][4]
    float* __restrict__ hlast_out)          // [B][32]
{
    const int ltid = threadIdx.x;
    const int l    = ltid & 63;
    const int w    = ltid >> 6;             // wave 0/1
    const int row  = l & 15;                // batch-within-tile
    const int q    = l >> 4;                // k-group 0..3
    const int base = blockIdx.x * 16;

    __shared__ unsigned int mlds[512];      // [t][16] spike masks
    __shared__ alignas(16) __bf16 hlds[640];   // [16][40]
    __shared__ alignas(16) __bf16 zlds[1152];  // [16][72]

    for (int i = ltid; i < 512; i += 128) {
        int j = i >> 5, t = i & 31;
        mlds[t * 16 + j] = spk[(size_t)(base + j) * 32 + t];
    }
    for (int i = ltid; i < 640; i += 128) hlds[i] = (__bf16)0.f;

    // wave w: tiles T = 2g + w, g = gate index (i,f,g,o) -> channels 16w+4q+j
    bf16x8 wih[4], whh[4];
    f32x4  bfr[4];
    #pragma unroll
    for (int g = 0; g < 4; g++) {
        const int T = 2 * g + w;
        wih[g] = ldfrag(w_ih + (size_t)(16 * T + row) * 32 + 8 * q);
        whh[g] = ldfrag(w_hh + (size_t)(16 * T + row) * 32 + 8 * q);
        const float* ba = b_ih + 16 * T + 4 * q;
        const float* bb = b_hh + 16 * T + 4 * q;
        f32x4 bf;
        #pragma unroll
        for (int i = 0; i < 4; i++) bf[i] = ba[i] + bb[i];
        bfr[g] = bf;
    }

    float cst[4], hq[4];
    #pragma unroll
    for (int i = 0; i < 4; i++) { cst[i] = 0.f; hq[i] = 0.f; }
    __syncthreads();

    #pragma unroll 1
    for (int t = 0; t < 32; t++) {
        unsigned int m  = mlds[t * 16 + row];
        unsigned int by = (m >> (q * 8)) & 0xFFu;
        union { bf16x8 v; unsigned int u[4]; } a1;
        a1.u[0] = ((by & 1u)        * 0x3F80u) | (((by >> 1) & 1u) * 0x3F800000u);
        a1.u[1] = (((by >> 2) & 1u) * 0x3F80u) | (((by >> 3) & 1u) * 0x3F800000u);
        a1.u[2] = (((by >> 4) & 1u) * 0x3F80u) | (((by >> 5) & 1u) * 0x3F800000u);
        a1.u[3] = (((by >> 6) & 1u) * 0x3F80u) | (((by >> 7) & 1u) * 0x3F800000u);
        bf16x8 a2 = *reinterpret_cast<bf16x8*>(&hlds[row * 40 + q * 8]);
        __syncthreads();                    // all h reads done

        f32x4 acc[4];
        #pragma unroll
        for (int g = 0; g < 4; g++) {
            acc[g] = __builtin_amdgcn_mfma_f32_16x16x32_bf16(wih[g], a1.v, bfr[g], 0, 0, 0);
            acc[g] = __builtin_amdgcn_mfma_f32_16x16x32_bf16(whh[g], a2,   acc[g], 0, 0, 0);
        }

        #pragma unroll
        for (int j = 0; j < 4; j++) {
            float iv = sigm(acc[0][j]);
            float fv = sigm(acc[1][j]);
            float gv = tanh_(acc[2][j]);
            float ov = sigm(acc[3][j]);
            cst[j] = fmaf(fv, cst[j], iv * gv);
            hq[j]  = ov * tanh_(cst[j]);
        }

        bf16x4 hv;
        #pragma unroll
        for (int j = 0; j < 4; j++) hv[j] = (__bf16)hq[j];
        *reinterpret_cast<bf16x4*>(&hlds[row * 40 + 16 * w + 4 * q]) = hv;
        __syncthreads();                    // all h writes done
    }

    // ---- h_last output (fp32, from registers) ----
    {
        f32x4 lo;
        #pragma unroll
        for (int j = 0; j < 4; j++) lo[j] = hq[j];
        *reinterpret_cast<f32x4*>(hlast_out + (size_t)(base + row) * 32 + 16 * w + 4 * q) = lo;
    }

    // ---- FC head (tiles split across the two waves) ----
    bf16x8 hf = *reinterpret_cast<bf16x8*>(&hlds[row * 40 + 8 * q]);
    bf16x8 spf;
    {
        const float* sp = spatial_in + (size_t)(base + row) * 32 + 8 * q;
        #pragma unroll
        for (int i = 0; i < 8; i++) spf[i] = (__bf16)sp[i];
    }

    // fc1: 4 tiles; wave w does T = {w, 2+w}
    #pragma unroll
    for (int g = 0; g < 2; g++) {
        const int T = 2 * g + w;
        bf16x8 x0 = ldfrag(fc1w + (size_t)(16 * T + row) * 64 + 8 * q);
        bf16x8 x1 = ldfrag(fc1w + (size_t)(16 * T + row) * 64 + 32 + 8 * q);
        f32x4 c;
        #pragma unroll
        for (int i = 0; i < 4; i++) c[i] = fc1b[16 * T + 4 * q + i];
        f32x4 a = __builtin_amdgcn_mfma_f32_16x16x32_bf16(x0, hf,  c, 0, 0, 0);
        a       = __builtin_amdgcn_mfma_f32_16x16x32_bf16(x1, spf, a, 0, 0, 0);
        bf16x4 zv;
        #pragma unroll
        for (int i = 0; i < 4; i++) zv[i] = (__bf16)fmaxf(a[i], 0.f);
        *reinterpret_cast<bf16x4*>(&zlds[row * 72 + 16 * T + 4 * q]) = zv;
    }
    __syncthreads();
    bf16x8 z1f0 = *reinterpret_cast<bf16x8*>(&zlds[row * 72 + 8 * q]);
    bf16x8 z1f1 = *reinterpret_cast<bf16x8*>(&zlds[row * 72 + 32 + 8 * q]);

    // fc2: 2 tiles; wave w does tile w
    {
        const int T = w;
        bf16x8 x0 = ldfrag(fc2w + (size_t)(16 * T + row) * 64 + 8 * q);
        bf16x8 x1 = ldfrag(fc2w + (size_t)(16 * T + row) * 64 + 32 + 8 * q);
        f32x4 c;
        #pragma unroll
        for (int i = 0; i < 4; i++) c[i] = fc2b[16 * T + 4 * q + i];
        f32x4 a = __builtin_amdgcn_mfma_f32_16x16x32_bf16(x0, z1f0, c, 0, 0, 0);
        a       = __builtin_amdgcn_mfma_f32_16x16x32_bf16(x1, z1f1, a, 0, 0, 0);
        bf16x4 zv;
        #pragma unroll
        for (int i = 0; i < 4; i++) zv[i] = (__bf16)fmaxf(a[i], 0.f);
        *reinterpret_cast<bf16x4*>(&hlds[row * 40 + 16 * T + 4 * q]) = zv;
    }
    __syncthreads();

    // fc3: wave 0 only
    if (w == 0) {
        bf16x8 z2f = *reinterpret_cast<bf16x8*>(&hlds[row * 40 + 8 * q]);
        bf16x8 x3  = ldfrag(fc3w + (size_t)(row & 3) * 32 + 8 * q);
        f32x4 c;
        #pragma unroll
        for (int i = 0; i < 4; i++) c[i] = fc3b[i];
        f32x4 o = __builtin_amdgcn_mfma_f32_16x16x32_bf16(x3, z2f, c, 0, 0, 0);
        if (l < 16)
            *reinterpret_cast<f32x4*>(out0 + (size_t)(base + row) * 4) = o;
    }
}

// ---------------------------------------------------------------------------
extern "C" void kernel_launch(void* const* d_in, const int* in_sizes, int n_in,
                              void* d_out, int out_size, void* d_ws, size_t ws_size,
                              hipStream_t stream) {
    const float* x    = (const float*)d_in[0];
    const float* w1   = (const float*)d_in[1];
    const float* b1   = (const float*)d_in[2];
    const float* g1   = (const float*)d_in[3];
    const float* be1  = (const float*)d_in[4];
    const float* m1   = (const float*)d_in[5];
    const float* v1   = (const float*)d_in[6];
    const float* w2   = (const float*)d_in[7];
    const float* b2   = (const float*)d_in[8];
    const float* g2   = (const float*)d_in[9];
    const float* be2  = (const float*)d_in[10];
    const float* m2   = (const float*)d_in[11];
    const float* v2   = (const float*)d_in[12];
    const float* w3   = (const float*)d_in[13];
    const float* b3   = (const float*)d_in[14];
    const float* g3   = (const float*)d_in[15];
    const float* be3  = (const float*)d_in[16];
    const float* m3   = (const float*)d_in[17];
    const float* v3   = (const float*)d_in[18];
    const float* w_ih = (const float*)d_in[19];
    const float* w_hh = (const float*)d_in[20];
    const float* b_ih = (const float*)d_in[21];
    const float* b_hh = (const float*)d_in[22];
    const float* fc1w = (const float*)d_in[23];
    const float* fc1b = (const float*)d_in[24];
    const float* fc2w = (const float*)d_in[25];
    const float* fc2b = (const float*)d_in[26];
    const float* fc3w = (const float*)d_in[27];
    const float* fc3b = (const float*)d_in[28];

    float* out0    = (float*)d_out;                 // [8192][4]
    float* spatial = out0 + (size_t)NB * 4;         // [8192][32]
    float* hlast   = spatial + (size_t)NB * 32;     // [8192][32]
    unsigned int* spk = (unsigned int*)d_ws;        // [8192][32] bitmasks
    float* wsf = (float*)d_ws + WSF_OFF;            // folded weights (9.2 KB)

    hipLaunchKernelGGL(fold_kernel, dim3(9), dim3(256), 0, stream,
                       w1, b1, g1, be1, m1, v1,
                       w2, b2, g2, be2, m2, v2,
                       w3, b3, g3, be3, m3, v3, wsf);

    hipLaunchKernelGGL(conv_lif_kernel, dim3(NB / 2), dim3(256), 0, stream,
                       x, wsf, spatial, spk);

    hipLaunchKernelGGL(lstm_fc_mfma_kernel, dim3(NB / 16), dim3(128), 0, stream,
                       spk, w_ih, w_hh, b_ih, b_hh,
                       fc1w, fc1b, fc2w, fc2b, fc3w, fc3b,
                       spatial, out0, hlast);
}